// Round 6
// baseline (909.135 us; speedup 1.0000x reference)
//
#include <hip/hip_runtime.h>
#include <stdint.h>

#define DEVI __device__ __forceinline__

typedef unsigned short u16;
typedef unsigned int u32;
typedef __attribute__((ext_vector_type(4))) unsigned short u16x4;
typedef __attribute__((ext_vector_type(8))) unsigned short u16x8;
typedef __attribute__((ext_vector_type(4))) float f32x4;
typedef __attribute__((ext_vector_type(8))) _Float16 f16x8;

static constexpr int NT = 4096;   // tokens
static constexpr int D  = 512;    // channels per head
static constexpr int NH = 4;      // heads
static constexpr int KS = 4;      // split-K factor for PV

DEVI u16 f2h(float f) {
  _Float16 h = (_Float16)f;
  union { _Float16 h; u16 u; } v; v.h = h;
  return v.u;
}

// order-preserving float<->uint for atomicMax on floats (finite values encode > 0)
DEVI u32 enc_ord(float f) {
  u32 u = __float_as_uint(f);
  return (u & 0x80000000u) ? ~u : (u | 0x80000000u);
}
DEVI float dec_ord(u32 k) {
  u32 u = (k & 0x80000000u) ? (k ^ 0x80000000u) : ~k;
  return __uint_as_float(u);
}

DEVI void gld_lds16(const u16* g, u16* l) {
  __builtin_amdgcn_global_load_lds((const __attribute__((address_space(1))) void*)g,
                                   (__attribute__((address_space(3))) void*)l, 16, 0, 0);
}

enum { OUT_F32 = 0, OUT_F16 = 2, OUT_RES = 3, OUT_SMAX = 4 };

// C[M,N] = A[M,K] @ B[N,K]^T  (f16 in, f32 acc). 128x128 tile, BK=32, 4 waves.
// OUT_SMAX: write f16 C and update global row/col max (ordered-u32 atomics).
template<int OUT>
__global__ __launch_bounds__(256)
void gemm_bt(const u16* __restrict__ A, int lda, size_t zsA,
             const u16* __restrict__ B, int ldb, size_t zsB,
             void* __restrict__ Cp, int ldc, size_t zsC,
             const float* __restrict__ res, int K,
             u32* __restrict__ rmg, u32* __restrict__ cmg)
{
  __shared__ u16 As[128 * 32];
  __shared__ u16 Bs[128 * 32];
  __shared__ u32 rmaxs[128], cmaxs[128];
  A += blockIdx.z * zsA;
  B += blockIdx.z * zsB;
  const int tid = threadIdx.x;
  const int lane = tid & 63, w = tid >> 6;
  const int wr = w >> 1, wc = w & 1;
  const int m0 = blockIdx.y * 128, n0 = blockIdx.x * 128;

  if (OUT == OUT_SMAX && tid < 128) { rmaxs[tid] = 0u; cmaxs[tid] = 0u; }

  f32x4 acc[4][4] = {};

  for (int k0 = 0; k0 < K; k0 += 32) {
    __syncthreads();
#pragma unroll
    for (int p = 0; p < 2; ++p) {
      int id = p * 256 + tid;
      int row = id >> 2, q = id & 3;
      gld_lds16(A + (size_t)(m0 + row) * lda + k0 + q * 8, As + id * 8);
      gld_lds16(B + (size_t)(n0 + row) * ldb + k0 + q * 8, Bs + id * 8);
    }
    __syncthreads();
    f16x8 af[4], bfv[4];
#pragma unroll
    for (int i = 0; i < 4; ++i)
      af[i] = *(const f16x8*)(As + (wr * 64 + i * 16 + (lane & 15)) * 32 + (lane >> 4) * 8);
#pragma unroll
    for (int i = 0; i < 4; ++i)
      bfv[i] = *(const f16x8*)(Bs + (wc * 64 + i * 16 + (lane & 15)) * 32 + (lane >> 4) * 8);
#pragma unroll
    for (int i = 0; i < 4; ++i)
#pragma unroll
      for (int j = 0; j < 4; ++j)
        acc[i][j] = __builtin_amdgcn_mfma_f32_16x16x32_f16(af[i], bfv[j], acc[i][j], 0, 0, 0);
  }

#pragma unroll
  for (int i = 0; i < 4; ++i) {
    int rl0 = wr * 64 + i * 16 + (lane >> 4) * 4;
#pragma unroll
    for (int j = 0; j < 4; ++j) {
      int c = n0 + wc * 64 + j * 16 + (lane & 15);
#pragma unroll
      for (int e = 0; e < 4; ++e) {
        size_t idx = blockIdx.z * zsC + (size_t)(m0 + rl0 + e) * ldc + c;
        float v = acc[i][j][e];
        if (OUT == OUT_F32)  ((float*)Cp)[idx] = v;
        if (OUT == OUT_F16)  ((u16*)Cp)[idx] = f2h(v);
        if (OUT == OUT_RES)  ((float*)Cp)[idx] = res[idx] + v;
        if (OUT == OUT_SMAX) ((u16*)Cp)[idx] = f2h(v);
      }
    }
  }

  if (OUT == OUT_SMAX) {
#pragma unroll
    for (int i = 0; i < 4; ++i) {
      int rl0 = wr * 64 + i * 16 + (lane >> 4) * 4;
#pragma unroll
      for (int e = 0; e < 4; ++e) {
        float m = fmaxf(fmaxf(acc[i][0][e], acc[i][1][e]), fmaxf(acc[i][2][e], acc[i][3][e]));
        atomicMax(&rmaxs[rl0 + e], enc_ord(m));
      }
    }
#pragma unroll
    for (int j = 0; j < 4; ++j) {
      float m = -3e38f;
#pragma unroll
      for (int i = 0; i < 4; ++i)
#pragma unroll
        for (int e = 0; e < 4; ++e) m = fmaxf(m, acc[i][j][e]);
      atomicMax(&cmaxs[wc * 64 + j * 16 + (lane & 15)], enc_ord(m));
    }
    __syncthreads();
    if (tid < 128) {
      atomicMax(rmg + m0 + tid, rmaxs[tid]);
      atomicMax(cmg + n0 + tid, cmaxs[tid]);
    }
  }
}

// dir1 PV, split-K: part[z][M][D] = exp(S[m, kb:kb+Ksl]-rowm[m]) @ B[:, kb:...]^T (unscaled)
// lpart[z][m] = partial row sums of the exps (written by blockIdx.x==0)
__global__ __launch_bounds__(256)
void pv_row(const u16* __restrict__ S, const u32* __restrict__ rowm_u,
            const u16* __restrict__ B,   // [D][NT]
            float* __restrict__ part, float* __restrict__ lpart, int Ksl)
{
  __shared__ u16 As[128 * 40];
  __shared__ u16 Bs[128 * 32];
  __shared__ float rmv[128];
  __shared__ float ps[4][128];
  const int tid = threadIdx.x;
  const int lane = tid & 63, w = tid >> 6;
  const int wr = w >> 1, wc = w & 1;
  const int m0 = blockIdx.y * 128, n0 = blockIdx.x * 128;
  const int kb = blockIdx.z * Ksl;
  if (tid < 128) rmv[tid] = dec_ord(rowm_u[m0 + tid]);

  f32x4 acc[4][4] = {};
  float sacc0 = 0.f, sacc1 = 0.f;

  for (int k0 = 0; k0 < Ksl; k0 += 32) {
    __syncthreads();
#pragma unroll
    for (int p = 0; p < 2; ++p) {
      int id = p * 256 + tid;
      int row = id >> 2, q = id & 3;
      gld_lds16(B + (size_t)(n0 + row) * NT + kb + k0 + q * 8, Bs + id * 8);
    }
#pragma unroll
    for (int p = 0; p < 2; ++p) {
      int flat = p * 2048 + tid * 8;
      int row = flat >> 5, k = flat & 31;
      f16x8 sv = *(const f16x8*)(S + (size_t)(m0 + row) * NT + kb + k0 + k);
      float m = rmv[row];
      u16x8 pk;
      float rs = 0.f;
#pragma unroll
      for (int j = 0; j < 8; ++j) {
        float e = __expf((float)sv[j] - m);
        rs += e;
        pk[j] = f2h(e);
      }
      *(u16x8*)(As + row * 40 + k) = pk;
      if (p == 0) sacc0 += rs; else sacc1 += rs;
    }
    __syncthreads();
    f16x8 af[4], bfv[4];
#pragma unroll
    for (int i = 0; i < 4; ++i)
      af[i] = *(const f16x8*)(As + (wr * 64 + i * 16 + (lane & 15)) * 40 + (lane >> 4) * 8);
#pragma unroll
    for (int i = 0; i < 4; ++i)
      bfv[i] = *(const f16x8*)(Bs + (wc * 64 + i * 16 + (lane & 15)) * 32 + (lane >> 4) * 8);
#pragma unroll
    for (int i = 0; i < 4; ++i)
#pragma unroll
      for (int j = 0; j < 4; ++j)
        acc[i][j] = __builtin_amdgcn_mfma_f32_16x16x32_f16(af[i], bfv[j], acc[i][j], 0, 0, 0);
  }

  float* out = part + (size_t)blockIdx.z * NT * D;
#pragma unroll
  for (int i = 0; i < 4; ++i) {
    int r0 = m0 + wr * 64 + i * 16 + (lane >> 4) * 4;
#pragma unroll
    for (int j = 0; j < 4; ++j) {
      int c = n0 + wc * 64 + j * 16 + (lane & 15);
#pragma unroll
      for (int e = 0; e < 4; ++e)
        out[(size_t)(r0 + e) * D + c] = acc[i][j][e];
    }
  }

  // partial row sums: 4 threads per row (p=0 rows 0..63, p=1 rows 64..127)
  __syncthreads();
  ps[tid & 3][tid >> 2] = sacc0;
  __syncthreads();
  float s0 = (tid < 128) ? (ps[0][tid] + ps[1][tid] + ps[2][tid] + ps[3][tid]) : 0.f;
  __syncthreads();
  ps[tid & 3][tid >> 2] = sacc1;
  __syncthreads();
  if (blockIdx.x == 0 && tid < 128) {
    float v;
    if (tid < 64) v = s0;                  // rows 0..63 from first pass
    else v = 0.f;
    // recompute cleanly: rows 0..63 use s0 (indexed by row), rows 64..127 from second pass
    if (tid < 64) {
      lpart[(size_t)blockIdx.z * NT + m0 + tid] = s0;
    } else {
      float s1 = ps[0][tid - 64] + ps[1][tid - 64] + ps[2][tid - 64] + ps[3][tid - 64];
      lpart[(size_t)blockIdx.z * NT + m0 + tid] = s1;
      (void)v;
    }
  }
}

// dir2 PV, split-K: part[z][M][D] = exp(S[kb:kb+Ksl, m]^T - colm[m]) @ B^T (unscaled)
// lpart[z][m] = partial col sums
__global__ __launch_bounds__(256)
void pv_col(const u16* __restrict__ S, const u32* __restrict__ colm_u,
            const u16* __restrict__ B,   // [D][NT]
            float* __restrict__ part, float* __restrict__ lpart, int Ksl)
{
  __shared__ u16 As[128 * 40];
  __shared__ u16 Bs[128 * 32];
  __shared__ float cms[128];
  __shared__ float ps2[32][128];
  const int tid = threadIdx.x;
  const int lane = tid & 63, w = tid >> 6;
  const int wr = w >> 1, wc = w & 1;
  const int m0 = blockIdx.y * 128, n0 = blockIdx.x * 128;
  const int kb = blockIdx.z * Ksl;
  if (tid < 128) cms[tid] = dec_ord(colm_u[m0 + tid]);

  f32x4 acc[4][4] = {};
  float cs0[8] = {}, cs1[8] = {};

  for (int k0 = 0; k0 < Ksl; k0 += 32) {
    __syncthreads();
#pragma unroll
    for (int p = 0; p < 2; ++p) {
      int id = p * 256 + tid;
      int row = id >> 2, q = id & 3;
      gld_lds16(B + (size_t)(n0 + row) * NT + kb + k0 + q * 8, Bs + id * 8);
    }
    // A tile transposed: As[m][k] = exp(S[kglob][m0+m] - cms[m])
#pragma unroll
    for (int p = 0; p < 2; ++p) {
      int id = p * 256 + tid;
      int k = id >> 4, m8 = (id & 15) * 8;
      f16x8 sv = *(const f16x8*)(S + (size_t)(kb + k0 + k) * NT + m0 + m8);
#pragma unroll
      for (int j = 0; j < 8; ++j) {
        float e = __expf((float)sv[j] - cms[m8 + j]);
        if (p == 0) cs0[j] += e; else cs1[j] += e;
        As[(m8 + j) * 40 + k] = f2h(e);
      }
    }
    __syncthreads();
    f16x8 af[4], bfv[4];
#pragma unroll
    for (int i = 0; i < 4; ++i)
      af[i] = *(const f16x8*)(As + (wr * 64 + i * 16 + (lane & 15)) * 40 + (lane >> 4) * 8);
#pragma unroll
    for (int i = 0; i < 4; ++i)
      bfv[i] = *(const f16x8*)(Bs + (wc * 64 + i * 16 + (lane & 15)) * 32 + (lane >> 4) * 8);
#pragma unroll
    for (int i = 0; i < 4; ++i)
#pragma unroll
      for (int j = 0; j < 4; ++j)
        acc[i][j] = __builtin_amdgcn_mfma_f32_16x16x32_f16(af[i], bfv[j], acc[i][j], 0, 0, 0);
  }

  float* out = part + (size_t)blockIdx.z * NT * D;
#pragma unroll
  for (int i = 0; i < 4; ++i) {
    int r0 = m0 + wr * 64 + i * 16 + (lane >> 4) * 4;
#pragma unroll
    for (int j = 0; j < 4; ++j) {
      int c = n0 + wc * 64 + j * 16 + (lane & 15);
#pragma unroll
      for (int e = 0; e < 4; ++e)
        out[(size_t)(r0 + e) * D + c] = acc[i][j][e];
    }
  }

  __syncthreads();
  {
    int k0i = tid >> 4, m8 = (tid & 15) * 8;
#pragma unroll
    for (int j = 0; j < 8; ++j) ps2[k0i][m8 + j] = cs0[j];
#pragma unroll
    for (int j = 0; j < 8; ++j) ps2[16 + k0i][m8 + j] = cs1[j];
  }
  __syncthreads();
  if (blockIdx.x == 0 && tid < 128) {
    float s = 0.f;
#pragma unroll
    for (int g = 0; g < 32; ++g) s += ps2[g][tid];
    lpart[(size_t)blockIdx.z * NT + m0 + tid] = s;
  }
}

// out0 += (0.25/Lk[m]) * sum_z pk[z];  out1 += (0.25/Lq[m]) * sum_z pq[z]
__global__ __launch_bounds__(256)
void reduce2(const float* __restrict__ pk, const float* __restrict__ lk,
             const float* __restrict__ pq, const float* __restrict__ lq,
             float* __restrict__ out0, float* __restrict__ out1)
{
  const size_t i = ((size_t)blockIdx.x * 256 + threadIdx.x) * 4;
  const int m = (int)(i >> 9);   // i / D
  const size_t zs = (size_t)NT * D;
  float Lk = 0.f, Lq = 0.f;
#pragma unroll
  for (int z = 0; z < KS; ++z) { Lk += lk[(size_t)z * NT + m]; Lq += lq[(size_t)z * NT + m]; }
  f32x4 s = *(const f32x4*)(pk + i);
#pragma unroll
  for (int z = 1; z < KS; ++z) s += *(const f32x4*)(pk + z * zs + i);
  f32x4 o = *(const f32x4*)(out0 + i);
  *(f32x4*)(out0 + i) = o + s * (0.25f / Lk);
  f32x4 t = *(const f32x4*)(pq + i);
#pragma unroll
  for (int z = 1; z < KS; ++z) t += *(const f32x4*)(pq + z * zs + i);
  f32x4 p = *(const f32x4*)(out1 + i);
  *(f32x4*)(out1 + i) = p + t * (0.25f / Lq);
}

__global__ __launch_bounds__(256)
void cast_f32_f16(const float* __restrict__ in, u16* __restrict__ out, int n)
{
  int i = (blockIdx.x * 256 + threadIdx.x) * 8;
  if (i >= n) return;
  f32x4 a = *(const f32x4*)(in + i), b = *(const f32x4*)(in + i + 4);
  u16x8 s;
  s[0] = f2h(a[0]); s[1] = f2h(a[1]); s[2] = f2h(a[2]); s[3] = f2h(a[3]);
  s[4] = f2h(b[0]); s[5] = f2h(b[1]); s[6] = f2h(b[2]); s[7] = f2h(b[3]);
  *(u16x8*)(out + i) = s;
}

// out[c][r] = f16(in[r][c]);  64x64 tiles
__global__ __launch_bounds__(256)
void transpose_cast_f32(const float* __restrict__ in, int ldi,
                        u16* __restrict__ out, int ldo)
{
  __shared__ u16 t[64][72];
  int r0 = blockIdx.x * 64, c0 = blockIdx.y * 64;
  int t8 = threadIdx.x & 7, rr = threadIdx.x >> 3;
#pragma unroll
  for (int p = 0; p < 2; ++p) {
    int r = rr + p * 32;
    const float* src = in + (size_t)(r0 + r) * ldi + c0 + t8 * 8;
    f32x4 a = *(const f32x4*)src, b = *(const f32x4*)(src + 4);
    u16x8 s;
    s[0] = f2h(a[0]); s[1] = f2h(a[1]); s[2] = f2h(a[2]); s[3] = f2h(a[3]);
    s[4] = f2h(b[0]); s[5] = f2h(b[1]); s[6] = f2h(b[2]); s[7] = f2h(b[3]);
    *(u16x8*)&t[r][t8 * 8] = s;
  }
  __syncthreads();
#pragma unroll
  for (int p = 0; p < 2; ++p) {
    int c = rr + p * 32;
    u16x8 s;
#pragma unroll
    for (int j = 0; j < 8; ++j) s[j] = t[t8 * 8 + j][c];
    *(u16x8*)(out + (size_t)(c0 + c) * ldo + r0 + t8 * 8) = s;
  }
}

__global__ __launch_bounds__(256)
void transpose_f16(const u16* __restrict__ in, int ldi,
                   u16* __restrict__ out, int ldo)
{
  __shared__ u16 t[64][72];
  int r0 = blockIdx.x * 64, c0 = blockIdx.y * 64;
  int t8 = threadIdx.x & 7, rr = threadIdx.x >> 3;
#pragma unroll
  for (int p = 0; p < 2; ++p) {
    int r = rr + p * 32;
    *(u16x8*)&t[r][t8 * 8] = *(const u16x8*)(in + (size_t)(r0 + r) * ldi + c0 + t8 * 8);
  }
  __syncthreads();
#pragma unroll
  for (int p = 0; p < 2; ++p) {
    int c = rr + p * 32;
    u16x8 s;
#pragma unroll
    for (int j = 0; j < 8; ++j) s[j] = t[t8 * 8 + j][c];
    *(u16x8*)(out + (size_t)(c0 + c) * ldo + r0 + t8 * 8) = s;
  }
}

extern "C" void kernel_launch(void* const* d_in, const int* in_sizes, int n_in,
                              void* d_out, int out_size, void* d_ws, size_t ws_size,
                              hipStream_t stream)
{
  const float* x_k    = (const float*)d_in[0];
  const float* x_q    = (const float*)d_in[1];
  const float* k_w    = (const float*)d_in[2];
  const float* q_w    = (const float*)d_in[3];
  const float* attn_w = (const float*)d_in[4];
  const float* proj_w = (const float*)d_in[5];
  float* out0 = (float*)d_out;                 // doubles as aggk accumulator
  float* out1 = out0 + (size_t)NT * D;         // doubles as aggq accumulator

  char* wptr = (char*)d_ws;
  auto alloc = [&](size_t bytes) { char* p = wptr; wptr += (bytes + 255) & ~(size_t)255; return p; };
  u16*   pb     = (u16*)  alloc((size_t)D * D * 2);
  u16*   pbT    = (u16*)  alloc((size_t)D * D * 2);
  u16*   XKall  = (u16*)  alloc((size_t)NT * NH * D * 2);   // [4096][2048]
  u16*   XKTall = (u16*)  alloc((size_t)NT * NH * D * 2);   // [2048][4096]
  u16*   XQTall = (u16*)  alloc((size_t)NT * NH * D * 2);   // [2048][4096]
  u16*   Kpall  = (u16*)  alloc((size_t)NH * NT * D * 2);   // [4][4096][512]
  float* partK  = (float*)alloc((size_t)KS * NT * D * 4);   // 32 MB
  float* partQ  = (float*)alloc((size_t)KS * NT * D * 4);   // 32 MB
  float* lk     = (float*)alloc((size_t)KS * NT * 4);
  float* lq     = (float*)alloc((size_t)KS * NT * 4);
  u32*   rowm_u = (u32*)  alloc((size_t)NT * 4);
  u32*   colm_u = (u32*)  alloc((size_t)NT * 4);            // contiguous with rowm_u
  char*  Sreg   = alloc((size_t)NT * NT * 2);               // S f16; prep scratch aliased below
  u16*   S      = (u16*)Sreg;
  // prep-only scratch aliased into the (not yet used) S region (30MB <= 32MB)
  char* sp = Sreg;
  auto salloc = [&](size_t bytes) { char* p = sp; sp += (bytes + 255) & ~(size_t)255; return p; };
  u16* xkb   = (u16*)salloc((size_t)NT * D * 2);
  u16* xqb   = (u16*)salloc((size_t)NT * D * 2);
  u16* kwb   = (u16*)salloc((size_t)NH * D * D * 2);
  u16* qwb   = (u16*)salloc((size_t)NH * D * D * 2);
  u16* Abf   = (u16*)salloc((size_t)NH * D * D * 2);
  u16* XQall = (u16*)salloc((size_t)NT * NH * D * 2);

  // ---- prep: casts + projections (all heads batched) ----
  cast_f32_f16<<<NT * D / 2048, 256, 0, stream>>>(x_k, xkb, NT * D);
  cast_f32_f16<<<NT * D / 2048, 256, 0, stream>>>(x_q, xqb, NT * D);
  cast_f32_f16<<<NH * D * D / 2048, 256, 0, stream>>>(k_w, kwb, NH * D * D);
  cast_f32_f16<<<NH * D * D / 2048, 256, 0, stream>>>(q_w, qwb, NH * D * D);
  cast_f32_f16<<<NH * D * D / 2048, 256, 0, stream>>>(attn_w, Abf, NH * D * D);
  cast_f32_f16<<<D * D / 2048, 256, 0, stream>>>(proj_w, pb, D * D);
  transpose_cast_f32<<<dim3(D / 64, D / 64), 256, 0, stream>>>(proj_w, D, pbT, D);

  gemm_bt<OUT_F16><<<dim3(NH * D / 128, NT / 128), 256, 0, stream>>>(
      xkb, D, 0, kwb, D, 0, XKall, NH * D, 0, nullptr, D, nullptr, nullptr);
  gemm_bt<OUT_F16><<<dim3(NH * D / 128, NT / 128), 256, 0, stream>>>(
      xqb, D, 0, qwb, D, 0, XQall, NH * D, 0, nullptr, D, nullptr, nullptr);
  transpose_f16<<<dim3(NT / 64, NH * D / 64), 256, 0, stream>>>(XKall, NH * D, XKTall, NT);
  transpose_f16<<<dim3(NT / 64, NH * D / 64), 256, 0, stream>>>(XQall, NH * D, XQTall, NT);
  gemm_bt<OUT_F16><<<dim3(D / 128, NT / 128, NH), 256, 0, stream>>>(
      XQall, NH * D, (size_t)D, Abf, D, (size_t)D * D, Kpall, D, (size_t)NT * D, nullptr, D,
      nullptr, nullptr);

  hipMemsetAsync(d_out, 0, (size_t)2 * NT * D * 4, stream);   // aggk+aggq accumulators

  // ---- per-head ----
  for (int h = 0; h < NH; ++h) {
    const u16* XKh  = XKall + (size_t)h * D;          // lda 2048
    const u16* XKTh = XKTall + (size_t)h * D * NT;    // ldb 4096
    const u16* XQTh = XQTall + (size_t)h * D * NT;
    const u16* Kph  = Kpall + (size_t)h * NT * D;     // ldb 512

    hipMemsetAsync(rowm_u, 0, (size_t)NT * 4 * 2, stream);    // rowm_u + colm_u

    // S = XK_h @ Kp_h^T  (f16) + fused row/col maxes
    gemm_bt<OUT_SMAX><<<dim3(NT / 128, NT / 128), 256, 0, stream>>>(
        XKh, NH * D, 0, Kph, D, 0, S, NT, 0, nullptr, D, rowm_u, colm_u);

    // dir1: partK[z] = exp(S-rowm) @ XQ_h, + partial row sums
    pv_row<<<dim3(D / 128, NT / 128, KS), 256, 0, stream>>>(
        S, rowm_u, XQTh, partK, lk, NT / KS);
    // dir2: partQ[z] = exp(S^T-colm) @ XK_h, + partial col sums
    pv_col<<<dim3(D / 128, NT / 128, KS), 256, 0, stream>>>(
        S, colm_u, XKTh, partQ, lq, NT / KS);

    // deterministic merge + softmax normalization + head-mean accumulate
    reduce2<<<NT * D / 1024, 256, 0, stream>>>(partK, lk, partQ, lq, out0, out1);
  }

  // ---- final projections + residual ----
  u16* kf16 = (u16*)partK;
  u16* qf16 = (u16*)partK + (size_t)NT * D;
  cast_f32_f16<<<NT * D / 2048, 256, 0, stream>>>(out0, kf16, NT * D);
  cast_f32_f16<<<NT * D / 2048, 256, 0, stream>>>(out1, qf16, NT * D);
  gemm_bt<OUT_RES><<<dim3(D / 128, NT / 128), 256, 0, stream>>>(
      kf16, D, 0, pb, D, 0, out0, D, 0, x_k, D, nullptr, nullptr);
  gemm_bt<OUT_RES><<<dim3(D / 128, NT / 128), 256, 0, stream>>>(
      qf16, D, 0, pbT, D, 0, out1, D, 0, x_q, D, nullptr, nullptr);
}

// Round 7
// 751.421 us; speedup vs baseline: 1.2099x; 1.2099x over previous
//
#include <hip/hip_runtime.h>
#include <stdint.h>

#define DEVI __device__ __forceinline__

typedef unsigned short u16;
typedef unsigned int u32;
typedef __attribute__((ext_vector_type(4))) unsigned short u16x4;
typedef __attribute__((ext_vector_type(8))) unsigned short u16x8;
typedef __attribute__((ext_vector_type(4))) float f32x4;
typedef __attribute__((ext_vector_type(8))) _Float16 f16x8;

static constexpr int NT = 4096;   // tokens
static constexpr int D  = 512;    // channels per head
static constexpr int NH = 4;      // heads
static constexpr int KS = 4;      // split-K factor for PV

DEVI u16 f2h(float f) {
  _Float16 h = (_Float16)f;
  union { _Float16 h; u16 u; } v; v.h = h;
  return v.u;
}

// order-preserving float<->uint for atomicMax on floats (finite values encode > 0)
DEVI u32 enc_ord(float f) {
  u32 u = __float_as_uint(f);
  return (u & 0x80000000u) ? ~u : (u | 0x80000000u);
}
DEVI float dec_ord(u32 k) {
  u32 u = (k & 0x80000000u) ? (k ^ 0x80000000u) : ~k;
  return __uint_as_float(u);
}

DEVI void gld_lds16(const u16* g, u16* l) {
  __builtin_amdgcn_global_load_lds((const __attribute__((address_space(1))) void*)g,
                                   (__attribute__((address_space(3))) void*)l, 16, 0, 0);
}

enum { OUT_F32 = 0, OUT_F16 = 2, OUT_RES = 3, OUT_SMAX = 4 };

// C[M,N] = A[M,K] @ B[N,K]^T  (f16 in, f32 acc). 128x128 tile, BK=32, 4 waves.
// OUT_SMAX: write f16 C and update global row/col max (ordered-u32 atomics).
template<int OUT>
__global__ __launch_bounds__(256)
void gemm_bt(const u16* __restrict__ A, int lda, size_t zsA,
             const u16* __restrict__ B, int ldb, size_t zsB,
             void* __restrict__ Cp, int ldc, size_t zsC,
             const float* __restrict__ res, int K,
             u32* __restrict__ rmg, u32* __restrict__ cmg)
{
  __shared__ u16 As[128 * 32];
  __shared__ u16 Bs[128 * 32];
  __shared__ u32 rmaxs[128], cmaxs[128];
  A += blockIdx.z * zsA;
  B += blockIdx.z * zsB;
  const int tid = threadIdx.x;
  const int lane = tid & 63, w = tid >> 6;
  const int wr = w >> 1, wc = w & 1;
  const int m0 = blockIdx.y * 128, n0 = blockIdx.x * 128;

  if (OUT == OUT_SMAX && tid < 128) { rmaxs[tid] = 0u; cmaxs[tid] = 0u; }

  f32x4 acc[4][4] = {};

  for (int k0 = 0; k0 < K; k0 += 32) {
    __syncthreads();
#pragma unroll
    for (int p = 0; p < 2; ++p) {
      int id = p * 256 + tid;
      int row = id >> 2, q = id & 3;
      gld_lds16(A + (size_t)(m0 + row) * lda + k0 + q * 8, As + id * 8);
      gld_lds16(B + (size_t)(n0 + row) * ldb + k0 + q * 8, Bs + id * 8);
    }
    __syncthreads();
    f16x8 af[4], bfv[4];
#pragma unroll
    for (int i = 0; i < 4; ++i)
      af[i] = *(const f16x8*)(As + (wr * 64 + i * 16 + (lane & 15)) * 32 + (lane >> 4) * 8);
#pragma unroll
    for (int i = 0; i < 4; ++i)
      bfv[i] = *(const f16x8*)(Bs + (wc * 64 + i * 16 + (lane & 15)) * 32 + (lane >> 4) * 8);
#pragma unroll
    for (int i = 0; i < 4; ++i)
#pragma unroll
      for (int j = 0; j < 4; ++j)
        acc[i][j] = __builtin_amdgcn_mfma_f32_16x16x32_f16(af[i], bfv[j], acc[i][j], 0, 0, 0);
  }

#pragma unroll
  for (int i = 0; i < 4; ++i) {
    int rl0 = wr * 64 + i * 16 + (lane >> 4) * 4;
#pragma unroll
    for (int j = 0; j < 4; ++j) {
      int c = n0 + wc * 64 + j * 16 + (lane & 15);
#pragma unroll
      for (int e = 0; e < 4; ++e) {
        size_t idx = blockIdx.z * zsC + (size_t)(m0 + rl0 + e) * ldc + c;
        float v = acc[i][j][e];
        if (OUT == OUT_F32)  ((float*)Cp)[idx] = v;
        if (OUT == OUT_F16)  ((u16*)Cp)[idx] = f2h(v);
        if (OUT == OUT_RES)  ((float*)Cp)[idx] = res[idx] + v;
        if (OUT == OUT_SMAX) ((u16*)Cp)[idx] = f2h(v);
      }
    }
  }

  if (OUT == OUT_SMAX) {
#pragma unroll
    for (int i = 0; i < 4; ++i) {
      int rl0 = wr * 64 + i * 16 + (lane >> 4) * 4;
#pragma unroll
      for (int e = 0; e < 4; ++e) {
        float m = fmaxf(fmaxf(acc[i][0][e], acc[i][1][e]), fmaxf(acc[i][2][e], acc[i][3][e]));
        atomicMax(&rmaxs[rl0 + e], enc_ord(m));
      }
    }
#pragma unroll
    for (int j = 0; j < 4; ++j) {
      float m = -3e38f;
#pragma unroll
      for (int i = 0; i < 4; ++i)
#pragma unroll
        for (int e = 0; e < 4; ++e) m = fmaxf(m, acc[i][j][e]);
      atomicMax(&cmaxs[wc * 64 + j * 16 + (lane & 15)], enc_ord(m));
    }
    __syncthreads();
    if (tid < 128) {
      atomicMax(rmg + m0 + tid, rmaxs[tid]);
      atomicMax(cmg + n0 + tid, cmaxs[tid]);
    }
  }
}

// dir1 PV, split-K: part[z][M][D] = exp(S[m, kb:kb+Ksl]-rowm[m]) @ B[:, kb:...]^T (unscaled)
// lpart[z][m] = partial row sums of the exps (written by blockIdx.x==0)
__global__ __launch_bounds__(256)
void pv_row(const u16* __restrict__ S, const u32* __restrict__ rowm_u,
            const u16* __restrict__ B,   // [D][NT]
            float* __restrict__ part, float* __restrict__ lpart, int Ksl)
{
  __shared__ u16 As[128 * 40];
  __shared__ u16 Bs[128 * 32];
  __shared__ float rmv[128];
  __shared__ float ps[4][128];
  const int tid = threadIdx.x;
  const int lane = tid & 63, w = tid >> 6;
  const int wr = w >> 1, wc = w & 1;
  const int m0 = blockIdx.y * 128, n0 = blockIdx.x * 128;
  const int kb = blockIdx.z * Ksl;
  if (tid < 128) rmv[tid] = dec_ord(rowm_u[m0 + tid]);

  f32x4 acc[4][4] = {};
  float sacc0 = 0.f, sacc1 = 0.f;

  for (int k0 = 0; k0 < Ksl; k0 += 32) {
    __syncthreads();
#pragma unroll
    for (int p = 0; p < 2; ++p) {
      int id = p * 256 + tid;
      int row = id >> 2, q = id & 3;
      gld_lds16(B + (size_t)(n0 + row) * NT + kb + k0 + q * 8, Bs + id * 8);
    }
#pragma unroll
    for (int p = 0; p < 2; ++p) {
      int flat = p * 2048 + tid * 8;
      int row = flat >> 5, k = flat & 31;
      f16x8 sv = *(const f16x8*)(S + (size_t)(m0 + row) * NT + kb + k0 + k);
      float m = rmv[row];
      u16x8 pk;
      float rs = 0.f;
#pragma unroll
      for (int j = 0; j < 8; ++j) {
        float e = __expf((float)sv[j] - m);
        rs += e;
        pk[j] = f2h(e);
      }
      *(u16x8*)(As + row * 40 + k) = pk;
      if (p == 0) sacc0 += rs; else sacc1 += rs;
    }
    __syncthreads();
    f16x8 af[4], bfv[4];
#pragma unroll
    for (int i = 0; i < 4; ++i)
      af[i] = *(const f16x8*)(As + (wr * 64 + i * 16 + (lane & 15)) * 40 + (lane >> 4) * 8);
#pragma unroll
    for (int i = 0; i < 4; ++i)
      bfv[i] = *(const f16x8*)(Bs + (wc * 64 + i * 16 + (lane & 15)) * 32 + (lane >> 4) * 8);
#pragma unroll
    for (int i = 0; i < 4; ++i)
#pragma unroll
      for (int j = 0; j < 4; ++j)
        acc[i][j] = __builtin_amdgcn_mfma_f32_16x16x32_f16(af[i], bfv[j], acc[i][j], 0, 0, 0);
  }

  float* out = part + (size_t)blockIdx.z * NT * D;
#pragma unroll
  for (int i = 0; i < 4; ++i) {
    int r0 = m0 + wr * 64 + i * 16 + (lane >> 4) * 4;
#pragma unroll
    for (int j = 0; j < 4; ++j) {
      int c = n0 + wc * 64 + j * 16 + (lane & 15);
#pragma unroll
      for (int e = 0; e < 4; ++e)
        out[(size_t)(r0 + e) * D + c] = acc[i][j][e];
    }
  }

  // partial row sums: 4 threads per row (p=0 rows 0..63, p=1 rows 64..127)
  __syncthreads();
  ps[tid & 3][tid >> 2] = sacc0;
  __syncthreads();
  float s0 = (tid < 128) ? (ps[0][tid] + ps[1][tid] + ps[2][tid] + ps[3][tid]) : 0.f;
  __syncthreads();
  ps[tid & 3][tid >> 2] = sacc1;
  __syncthreads();
  if (blockIdx.x == 0 && tid < 128) {
    if (tid < 64) {
      lpart[(size_t)blockIdx.z * NT + m0 + tid] = s0;
    } else {
      float s1 = ps[0][tid - 64] + ps[1][tid - 64] + ps[2][tid - 64] + ps[3][tid - 64];
      lpart[(size_t)blockIdx.z * NT + m0 + tid] = s1;
    }
  }
}

// dir2 PV, split-K: part[z][M][D] = exp(S[kb:kb+Ksl, m]^T - colm[m]) @ B^T (unscaled)
// lpart[z][m] = partial col sums.  LDS A-tile k-XOR swizzled to kill bank conflicts.
__global__ __launch_bounds__(256)
void pv_col(const u16* __restrict__ S, const u32* __restrict__ colm_u,
            const u16* __restrict__ B,   // [D][NT]
            float* __restrict__ part, float* __restrict__ lpart, int Ksl)
{
  __shared__ u16 As[128 * 40];
  __shared__ u16 Bs[128 * 32];
  __shared__ float cms[128];
  __shared__ float ps2[32][128];
  const int tid = threadIdx.x;
  const int lane = tid & 63, w = tid >> 6;
  const int wr = w >> 1, wc = w & 1;
  const int m0 = blockIdx.y * 128, n0 = blockIdx.x * 128;
  const int kb = blockIdx.z * Ksl;
  if (tid < 128) cms[tid] = dec_ord(colm_u[m0 + tid]);

  f32x4 acc[4][4] = {};
  float cs0[8] = {}, cs1[8] = {};

  for (int k0 = 0; k0 < Ksl; k0 += 32) {
    __syncthreads();
#pragma unroll
    for (int p = 0; p < 2; ++p) {
      int id = p * 256 + tid;
      int row = id >> 2, q = id & 3;
      gld_lds16(B + (size_t)(n0 + row) * NT + kb + k0 + q * 8, Bs + id * 8);
    }
    // A tile transposed: As[m][k ^ swz(m)] = exp(S[kglob][m0+m] - cms[m])
    // swz(m) = ((m>>3)&3)<<3 -- spreads the 8-row-stride writes over 4 banks groups,
    // preserves 8-elem contiguity + 16B alignment of frag reads (k bits 0..2 untouched).
#pragma unroll
    for (int p = 0; p < 2; ++p) {
      int id = p * 256 + tid;
      int k = id >> 4, m8 = (id & 15) * 8;
      int kc = k ^ ((id & 3) << 3);   // (m>>3)&3 == id&3 for all 8 j's
      f16x8 sv = *(const f16x8*)(S + (size_t)(kb + k0 + k) * NT + m0 + m8);
#pragma unroll
      for (int j = 0; j < 8; ++j) {
        float e = __expf((float)sv[j] - cms[m8 + j]);
        if (p == 0) cs0[j] += e; else cs1[j] += e;
        As[(m8 + j) * 40 + kc] = f2h(e);
      }
    }
    __syncthreads();
    f16x8 af[4], bfv[4];
#pragma unroll
    for (int i = 0; i < 4; ++i) {
      int r = wr * 64 + i * 16 + (lane & 15);
      int ko = (lane >> 4) * 8;
      af[i] = *(const f16x8*)(As + r * 40 + (ko ^ (((r >> 3) & 3) << 3)));
    }
#pragma unroll
    for (int i = 0; i < 4; ++i)
      bfv[i] = *(const f16x8*)(Bs + (wc * 64 + i * 16 + (lane & 15)) * 32 + (lane >> 4) * 8);
#pragma unroll
    for (int i = 0; i < 4; ++i)
#pragma unroll
      for (int j = 0; j < 4; ++j)
        acc[i][j] = __builtin_amdgcn_mfma_f32_16x16x32_f16(af[i], bfv[j], acc[i][j], 0, 0, 0);
  }

  float* out = part + (size_t)blockIdx.z * NT * D;
#pragma unroll
  for (int i = 0; i < 4; ++i) {
    int r0 = m0 + wr * 64 + i * 16 + (lane >> 4) * 4;
#pragma unroll
    for (int j = 0; j < 4; ++j) {
      int c = n0 + wc * 64 + j * 16 + (lane & 15);
#pragma unroll
      for (int e = 0; e < 4; ++e)
        out[(size_t)(r0 + e) * D + c] = acc[i][j][e];
    }
  }

  __syncthreads();
  {
    int k0i = tid >> 4, m8 = (tid & 15) * 8;
#pragma unroll
    for (int j = 0; j < 8; ++j) ps2[k0i][m8 + j] = cs0[j];
#pragma unroll
    for (int j = 0; j < 8; ++j) ps2[16 + k0i][m8 + j] = cs1[j];
  }
  __syncthreads();
  if (blockIdx.x == 0 && tid < 128) {
    float s = 0.f;
#pragma unroll
    for (int g = 0; g < 32; ++g) s += ps2[g][tid];
    lpart[(size_t)blockIdx.z * NT + m0 + tid] = s;
  }
}

// out0 += (0.25/Lk[m]) * sum_z pk[z];  out1 += (0.25/Lq[m]) * sum_z pq[z]
__global__ __launch_bounds__(256)
void reduce2(const float* __restrict__ pk, const float* __restrict__ lk,
             const float* __restrict__ pq, const float* __restrict__ lq,
             float* __restrict__ out0, float* __restrict__ out1)
{
  const size_t i = ((size_t)blockIdx.x * 256 + threadIdx.x) * 4;
  const int m = (int)(i >> 9);   // i / D
  const size_t zs = (size_t)NT * D;
  float Lk = 0.f, Lq = 0.f;
#pragma unroll
  for (int z = 0; z < KS; ++z) { Lk += lk[(size_t)z * NT + m]; Lq += lq[(size_t)z * NT + m]; }
  f32x4 s = *(const f32x4*)(pk + i);
#pragma unroll
  for (int z = 1; z < KS; ++z) s += *(const f32x4*)(pk + z * zs + i);
  f32x4 o = *(const f32x4*)(out0 + i);
  *(f32x4*)(out0 + i) = o + s * (0.25f / Lk);
  f32x4 t = *(const f32x4*)(pq + i);
#pragma unroll
  for (int z = 1; z < KS; ++z) t += *(const f32x4*)(pq + z * zs + i);
  f32x4 p = *(const f32x4*)(out1 + i);
  *(f32x4*)(out1 + i) = p + t * (0.25f / Lq);
}

__global__ __launch_bounds__(256)
void cast_f32_f16(const float* __restrict__ in, u16* __restrict__ out, int n)
{
  int i = (blockIdx.x * 256 + threadIdx.x) * 8;
  if (i >= n) return;
  f32x4 a = *(const f32x4*)(in + i), b = *(const f32x4*)(in + i + 4);
  u16x8 s;
  s[0] = f2h(a[0]); s[1] = f2h(a[1]); s[2] = f2h(a[2]); s[3] = f2h(a[3]);
  s[4] = f2h(b[0]); s[5] = f2h(b[1]); s[6] = f2h(b[2]); s[7] = f2h(b[3]);
  *(u16x8*)(out + i) = s;
}

// out[c][r] = f16(in[r][c]);  64x64 tiles
__global__ __launch_bounds__(256)
void transpose_cast_f32(const float* __restrict__ in, int ldi,
                        u16* __restrict__ out, int ldo)
{
  __shared__ u16 t[64][72];
  int r0 = blockIdx.x * 64, c0 = blockIdx.y * 64;
  int t8 = threadIdx.x & 7, rr = threadIdx.x >> 3;
#pragma unroll
  for (int p = 0; p < 2; ++p) {
    int r = rr + p * 32;
    const float* src = in + (size_t)(r0 + r) * ldi + c0 + t8 * 8;
    f32x4 a = *(const f32x4*)src, b = *(const f32x4*)(src + 4);
    u16x8 s;
    s[0] = f2h(a[0]); s[1] = f2h(a[1]); s[2] = f2h(a[2]); s[3] = f2h(a[3]);
    s[4] = f2h(b[0]); s[5] = f2h(b[1]); s[6] = f2h(b[2]); s[7] = f2h(b[3]);
    *(u16x8*)&t[r][t8 * 8] = s;
  }
  __syncthreads();
#pragma unroll
  for (int p = 0; p < 2; ++p) {
    int c = rr + p * 32;
    u16x8 s;
#pragma unroll
    for (int j = 0; j < 8; ++j) s[j] = t[t8 * 8 + j][c];
    *(u16x8*)(out + (size_t)(c0 + c) * ldo + r0 + t8 * 8) = s;
  }
}

__global__ __launch_bounds__(256)
void transpose_f16(const u16* __restrict__ in, int ldi,
                   u16* __restrict__ out, int ldo)
{
  __shared__ u16 t[64][72];
  int r0 = blockIdx.x * 64, c0 = blockIdx.y * 64;
  int t8 = threadIdx.x & 7, rr = threadIdx.x >> 3;
#pragma unroll
  for (int p = 0; p < 2; ++p) {
    int r = rr + p * 32;
    *(u16x8*)&t[r][t8 * 8] = *(const u16x8*)(in + (size_t)(r0 + r) * ldi + c0 + t8 * 8);
  }
  __syncthreads();
#pragma unroll
  for (int p = 0; p < 2; ++p) {
    int c = rr + p * 32;
    u16x8 s;
#pragma unroll
    for (int j = 0; j < 8; ++j) s[j] = t[t8 * 8 + j][c];
    *(u16x8*)(out + (size_t)(c0 + c) * ldo + r0 + t8 * 8) = s;
  }
}

extern "C" void kernel_launch(void* const* d_in, const int* in_sizes, int n_in,
                              void* d_out, int out_size, void* d_ws, size_t ws_size,
                              hipStream_t stream)
{
  const float* x_k    = (const float*)d_in[0];
  const float* x_q    = (const float*)d_in[1];
  const float* k_w    = (const float*)d_in[2];
  const float* q_w    = (const float*)d_in[3];
  const float* attn_w = (const float*)d_in[4];
  const float* proj_w = (const float*)d_in[5];
  float* out0 = (float*)d_out;                 // doubles as aggk accumulator
  float* out1 = out0 + (size_t)NT * D;         // doubles as aggq accumulator

  char* wptr = (char*)d_ws;
  auto alloc = [&](size_t bytes) { char* p = wptr; wptr += (bytes + 255) & ~(size_t)255; return p; };
  u16*   pb     = (u16*)  alloc((size_t)D * D * 2);
  u16*   pbT    = (u16*)  alloc((size_t)D * D * 2);
  u16*   XKall  = (u16*)  alloc((size_t)NT * NH * D * 2);   // [4096][2048]
  u16*   XKTall = (u16*)  alloc((size_t)NT * NH * D * 2);   // [2048][4096]
  u16*   XQTall = (u16*)  alloc((size_t)NT * NH * D * 2);   // [2048][4096]
  u16*   Kpall  = (u16*)  alloc((size_t)NH * NT * D * 2);   // [4][4096][512]
  float* partK  = (float*)alloc((size_t)KS * NT * D * 4);   // 32 MB
  float* partQ  = (float*)alloc((size_t)KS * NT * D * 4);   // 32 MB
  float* lk     = (float*)alloc((size_t)KS * NT * 4);
  float* lq     = (float*)alloc((size_t)KS * NT * 4);
  u32*   rowm_u = (u32*)  alloc((size_t)NT * 4);
  u32*   colm_u = (u32*)  alloc((size_t)NT * 4);            // contiguous with rowm_u
  char*  Sreg   = alloc((size_t)NT * NT * 2);               // S f16; prep scratch aliased below
  u16*   S      = (u16*)Sreg;
  // prep-only scratch aliased into the (not yet used) S region (30MB <= 32MB)
  char* sp = Sreg;
  auto salloc = [&](size_t bytes) { char* p = sp; sp += (bytes + 255) & ~(size_t)255; return p; };
  u16* xkb   = (u16*)salloc((size_t)NT * D * 2);
  u16* xqb   = (u16*)salloc((size_t)NT * D * 2);
  u16* kwb   = (u16*)salloc((size_t)NH * D * D * 2);
  u16* qwb   = (u16*)salloc((size_t)NH * D * D * 2);
  u16* Abf   = (u16*)salloc((size_t)NH * D * D * 2);
  u16* XQall = (u16*)salloc((size_t)NT * NH * D * 2);

  // ---- prep: casts + projections (all heads batched) ----
  cast_f32_f16<<<NT * D / 2048, 256, 0, stream>>>(x_k, xkb, NT * D);
  cast_f32_f16<<<NT * D / 2048, 256, 0, stream>>>(x_q, xqb, NT * D);
  cast_f32_f16<<<NH * D * D / 2048, 256, 0, stream>>>(k_w, kwb, NH * D * D);
  cast_f32_f16<<<NH * D * D / 2048, 256, 0, stream>>>(q_w, qwb, NH * D * D);
  cast_f32_f16<<<NH * D * D / 2048, 256, 0, stream>>>(attn_w, Abf, NH * D * D);
  cast_f32_f16<<<D * D / 2048, 256, 0, stream>>>(proj_w, pb, D * D);
  transpose_cast_f32<<<dim3(D / 64, D / 64), 256, 0, stream>>>(proj_w, D, pbT, D);

  gemm_bt<OUT_F16><<<dim3(NH * D / 128, NT / 128), 256, 0, stream>>>(
      xkb, D, 0, kwb, D, 0, XKall, NH * D, 0, nullptr, D, nullptr, nullptr);
  gemm_bt<OUT_F16><<<dim3(NH * D / 128, NT / 128), 256, 0, stream>>>(
      xqb, D, 0, qwb, D, 0, XQall, NH * D, 0, nullptr, D, nullptr, nullptr);
  transpose_f16<<<dim3(NT / 64, NH * D / 64), 256, 0, stream>>>(XKall, NH * D, XKTall, NT);
  transpose_f16<<<dim3(NT / 64, NH * D / 64), 256, 0, stream>>>(XQall, NH * D, XQTall, NT);
  gemm_bt<OUT_F16><<<dim3(D / 128, NT / 128, NH), 256, 0, stream>>>(
      XQall, NH * D, (size_t)D, Abf, D, (size_t)D * D, Kpall, D, (size_t)NT * D, nullptr, D,
      nullptr, nullptr);

  hipMemsetAsync(d_out, 0, (size_t)2 * NT * D * 4, stream);   // aggk+aggq accumulators

  // ---- per-head ----
  for (int h = 0; h < NH; ++h) {
    const u16* XKh  = XKall + (size_t)h * D;          // lda 2048
    const u16* XKTh = XKTall + (size_t)h * D * NT;    // ldb 4096
    const u16* XQTh = XQTall + (size_t)h * D * NT;
    const u16* Kph  = Kpall + (size_t)h * NT * D;     // ldb 512

    hipMemsetAsync(rowm_u, 0, (size_t)NT * 4 * 2, stream);    // rowm_u + colm_u

    // S = XK_h @ Kp_h^T  (f16) + fused row/col maxes
    gemm_bt<OUT_SMAX><<<dim3(NT / 128, NT / 128), 256, 0, stream>>>(
        XKh, NH * D, 0, Kph, D, 0, S, NT, 0, nullptr, D, rowm_u, colm_u);

    // dir1: partK[z] = exp(S-rowm) @ XQ_h, + partial row sums
    pv_row<<<dim3(D / 128, NT / 128, KS), 256, 0, stream>>>(
        S, rowm_u, XQTh, partK, lk, NT / KS);
    // dir2: partQ[z] = exp(S^T-colm) @ XK_h, + partial col sums
    pv_col<<<dim3(D / 128, NT / 128, KS), 256, 0, stream>>>(
        S, colm_u, XKTh, partQ, lq, NT / KS);

    // deterministic merge + softmax normalization + head-mean accumulate
    reduce2<<<NT * D / 1024, 256, 0, stream>>>(partK, lk, partQ, lq, out0, out1);
  }

  // ---- final projections + residual ----
  u16* kf16 = (u16*)partK;
  u16* qf16 = (u16*)partK + (size_t)NT * D;
  cast_f32_f16<<<NT * D / 2048, 256, 0, stream>>>(out0, kf16, NT * D);
  cast_f32_f16<<<NT * D / 2048, 256, 0, stream>>>(out1, qf16, NT * D);
  gemm_bt<OUT_RES><<<dim3(D / 128, NT / 128), 256, 0, stream>>>(
      kf16, D, 0, pb, D, 0, out0, D, 0, x_k, D, nullptr, nullptr);
  gemm_bt<OUT_RES><<<dim3(D / 128, NT / 128), 256, 0, stream>>>(
      qf16, D, 0, pbT, D, 0, out1, D, 0, x_q, D, nullptr, nullptr);
}